// Round 5
// baseline (170.707 us; speedup 1.0000x reference)
//
#include <hip/hip_runtime.h>
#include <math.h>

#define BB 64
#define SS 8192
#define IN_DIM 512
#define OUT_DIM 128
#define DVV 128
#define CHUNK 256
#define NCHUNK (SS / CHUNK)          // 32
#define NGRP 8                       // 32-lane groups per 256-thread block
#define RPG (CHUNK / NGRP)           // 32 rows per group
#define NPART (NCHUNK * NGRP)        // 256 partials per batch

// Kernel 1: qt[b] = (Wk @ (q[b] @ Wq)) / sqrt(OUT_DIM)   (512 threads, 4-way split-K)
__global__ __launch_bounds__(512) void qt_kernel(const float* __restrict__ q,
                          const float* __restrict__ Wq,
                          const float* __restrict__ Wk,
                          float* __restrict__ qt) {
    int b = blockIdx.x;
    int t = threadIdx.x;
    int e = t & 127;          // output index
    int h = t >> 7;           // split 0..3
    __shared__ float part[4][OUT_DIM];
    __shared__ float qs[OUT_DIM];

    const float* qb = q + (size_t)b * IN_DIM;
    float acc = 0.f;
    for (int i = h * (IN_DIM / 4); i < (h + 1) * (IN_DIM / 4); ++i)
        acc = fmaf(qb[i], Wq[(size_t)i * OUT_DIM + e], acc);
    part[h][e] = acc;
    __syncthreads();
    if (h == 0) qs[e] = part[0][e] + part[1][e] + part[2][e] + part[3][e];
    __syncthreads();

    float a2 = 0.f;
    const float* wkrow = Wk + (size_t)e * OUT_DIM;
    for (int i = h * (OUT_DIM / 4); i < (h + 1) * (OUT_DIM / 4); ++i)
        a2 = fmaf(wkrow[i], qs[i], a2);
    part[h][e] = a2;
    __syncthreads();
    if (h == 0)
        qt[(size_t)b * OUT_DIM + e] =
            (part[0][e] + part[1][e] + part[2][e] + part[3][e]) * 0.08838834764831845f;
}

// Kernel 2: barrier-free streaming kernel, scores staged in LDS (no spill).
// Each 32-lane group independently owns rows g+8j of its 256-row chunk.
// Phase A: stream k, butterfly dot -> lane 0 writes score to sc[]; group max
// tracked in a register (uniform across the group). Phase B: stream v; weight
// w = exp(sc[row]-m) recomputed per lane (LDS broadcast read, VALU is idle);
// per-lane l accumulates w once per row (uniform in group). Per-group
// (m, l, ctx[128]) partial written to global. NO __syncthreads anywhere;
// the only cross-phase dependency (sc) is same-wave, handled by lgkmcnt.
__global__ __launch_bounds__(256) void partial_kernel(
    const float* __restrict__ k, const float* __restrict__ v,
    const float* __restrict__ qt, float* __restrict__ ml,
    float* __restrict__ ctx) {
    int blk = blockIdx.x;
    int b = blk >> 5;          // / NCHUNK
    int c = blk & 31;
    int s0 = c * CHUNK;
    int t = threadIdx.x;
    int g = t >> 5;            // group 0..7
    int l32 = t & 31;

    __shared__ float sc[CHUNK];

    float4 qv = ((const float4*)(qt + (size_t)b * OUT_DIM))[l32];

    // float4 pointers; row stride = 32 float4s; group g handles rows g+8j
    const float4* k4 = (const float4*)(k + (size_t)b * SS * OUT_DIM)
                       + (size_t)(s0 + g) * (OUT_DIM / 4) + l32;
    const float4* v4 = (const float4*)(v + (size_t)b * SS * DVV)
                       + (size_t)(s0 + g) * (DVV / 4) + l32;

    float m = -INFINITY;
    #pragma unroll
    for (int j = 0; j < RPG; ++j) {
        float4 kv = k4[j * 8 * (OUT_DIM / 4)];
        float p = kv.x * qv.x + kv.y * qv.y + kv.z * qv.z + kv.w * qv.w;
        p += __shfl_xor(p, 1);
        p += __shfl_xor(p, 2);
        p += __shfl_xor(p, 4);
        p += __shfl_xor(p, 8);
        p += __shfl_xor(p, 16);
        if (l32 == 0) sc[g + 8 * j] = p;
        m = fmaxf(m, p);
    }

    float l = 0.f;
    float4 acc = make_float4(0.f, 0.f, 0.f, 0.f);
    #pragma unroll
    for (int j = 0; j < RPG; ++j) {
        float4 vv = v4[j * 8 * (DVV / 4)];
        float w = __expf(sc[g + 8 * j] - m);   // same-wave LDS, broadcast read
        l += w;
        acc.x = fmaf(w, vv.x, acc.x);
        acc.y = fmaf(w, vv.y, acc.y);
        acc.z = fmaf(w, vv.z, acc.z);
        acc.w = fmaf(w, vv.w, acc.w);
    }

    size_t gi = (size_t)blk * NGRP + g;      // (b*NCHUNK+c)*8+g
    ((float4*)(ctx + gi * DVV))[l32] = acc;
    if (l32 == 0) {
        ml[gi * 2 + 0] = m;
        ml[gi * 2 + 1] = l;
    }
}

// Kernel 3: merge 256 group-partials per batch with max-rescaling.
__global__ __launch_bounds__(256) void combine_kernel(
    const float* __restrict__ ml, const float* __restrict__ ctx,
    float* __restrict__ out) {
    int b = blockIdx.x;
    int t = threadIdx.x;    // 256
    __shared__ float sm[NPART], sl[NPART], sw[NPART];

    sm[t] = ml[((size_t)b * NPART + t) * 2 + 0];
    sl[t] = ml[((size_t)b * NPART + t) * 2 + 1];
    __syncthreads();

    float M = -INFINITY;
    #pragma unroll 8
    for (int i = 0; i < NPART; ++i) M = fmaxf(M, sm[i]);
    sw[t] = __expf(sm[t] - M);
    __syncthreads();

    if (t < DVV) {
        float L = 0.f;
        #pragma unroll 8
        for (int i = 0; i < NPART; ++i) L = fmaf(sl[i], sw[i], L);
        float acc = 0.f;
        const float* cb = ctx + (size_t)b * NPART * DVV + t;
        #pragma unroll 8
        for (int i = 0; i < NPART; ++i)
            acc = fmaf(sw[i], cb[(size_t)i * DVV], acc);
        out[(size_t)b * DVV + t] = acc / L;
    }
}

extern "C" void kernel_launch(void* const* d_in, const int* in_sizes, int n_in,
                              void* d_out, int out_size, void* d_ws, size_t ws_size,
                              hipStream_t stream) {
    const float* k  = (const float*)d_in[0];
    const float* q  = (const float*)d_in[1];
    const float* v  = (const float*)d_in[2];
    const float* Wk = (const float*)d_in[3];
    const float* Wq = (const float*)d_in[4];
    float* out = (float*)d_out;

    float* qt  = (float*)d_ws;                     // B*128
    float* ml  = qt + BB * OUT_DIM;                // B*256*2
    float* ctx = ml + (size_t)BB * NPART * 2;      // B*256*128 (8.4 MB)

    qt_kernel<<<BB, 512, 0, stream>>>(q, Wq, Wk, qt);
    partial_kernel<<<BB * NCHUNK, 256, 0, stream>>>(k, v, qt, ml, ctx);
    combine_kernel<<<BB, 256, 0, stream>>>(ml, ctx, out);
}

// Round 6
// 151.547 us; speedup vs baseline: 1.1264x; 1.1264x over previous
//
#include <hip/hip_runtime.h>
#include <math.h>

#define BB 64
#define SS 8192
#define IN_DIM 512
#define OUT_DIM 128
#define DVV 128
#define CHUNK 128
#define NCHUNK (SS / CHUNK)   // 64

// Kernel 1: qt[b] = (Wk @ (q[b] @ Wq)) / sqrt(OUT_DIM)   (512 threads, 4-way split-K)
__global__ __launch_bounds__(512) void qt_kernel(const float* __restrict__ q,
                          const float* __restrict__ Wq,
                          const float* __restrict__ Wk,
                          float* __restrict__ qt) {
    int b = blockIdx.x;
    int t = threadIdx.x;
    int e = t & 127;          // output index
    int h = t >> 7;           // split 0..3
    __shared__ float part[4][OUT_DIM];
    __shared__ float qs[OUT_DIM];

    const float* qb = q + (size_t)b * IN_DIM;
    float acc = 0.f;
    for (int i = h * (IN_DIM / 4); i < (h + 1) * (IN_DIM / 4); ++i)
        acc = fmaf(qb[i], Wq[(size_t)i * OUT_DIM + e], acc);
    part[h][e] = acc;
    __syncthreads();
    if (h == 0) qs[e] = part[0][e] + part[1][e] + part[2][e] + part[3][e];
    __syncthreads();

    float a2 = 0.f;
    const float* wkrow = Wk + (size_t)e * OUT_DIM;
    for (int i = h * (OUT_DIM / 4); i < (h + 1) * (OUT_DIM / 4); ++i)
        a2 = fmaf(wkrow[i], qs[i], a2);
    part[h][e] = a2;
    __syncthreads();
    if (h == 0)
        qt[(size_t)b * OUT_DIM + e] =
            (part[0][e] + part[1][e] + part[2][e] + part[3][e]) * 0.08838834764831845f;
}

// Kernel 2: R0's proven block-phased structure, CHUNK=128 (2x oversubscribed).
__global__ __launch_bounds__(256) void partial_kernel(
    const float* __restrict__ k, const float* __restrict__ v,
    const float* __restrict__ qt, float* __restrict__ ml,
    float* __restrict__ ctx) {
    int blk = blockIdx.x;
    int b = blk >> 6;          // / NCHUNK
    int c = blk & 63;
    int s0 = c * CHUNK;
    int t = threadIdx.x;
    int wave = t >> 6, lane = t & 63, half = lane >> 5, l32 = lane & 31;

    __shared__ float4 qts4[OUT_DIM / 4];
    __shared__ float sc[CHUNK];
    __shared__ float4 red[256];
    __shared__ float wred[4];

    if (t < OUT_DIM / 4)
        qts4[t] = ((const float4*)(qt + (size_t)b * OUT_DIM))[t];
    __syncthreads();

    // ---- Phase A: scores for CHUNK rows, float4 coalesced k loads ----
    const float4* k4 = (const float4*)(k + (size_t)b * SS * OUT_DIM);
    float4 qv = qts4[l32];
    for (int i = wave * 2 + half; i < CHUNK; i += 8) {
        float4 kv = k4[(size_t)(s0 + i) * (OUT_DIM / 4) + l32];
        float p = kv.x * qv.x + kv.y * qv.y + kv.z * qv.z + kv.w * qv.w;
        p += __shfl_xor(p, 1);
        p += __shfl_xor(p, 2);
        p += __shfl_xor(p, 4);
        p += __shfl_xor(p, 8);
        p += __shfl_xor(p, 16);
        if (l32 == 0) sc[i] = p;
    }
    __syncthreads();

    // ---- chunk max ----
    float m = -INFINITY;
    for (int i = t; i < CHUNK; i += 256) m = fmaxf(m, sc[i]);
    for (int d = 1; d < 64; d <<= 1) m = fmaxf(m, __shfl_xor(m, d));
    if (lane == 0) wred[wave] = m;
    __syncthreads();
    m = fmaxf(fmaxf(wred[0], wred[1]), fmaxf(wred[2], wred[3]));
    __syncthreads();  // protect wred reuse

    // ---- exp + chunk sum ----
    float lsum = 0.f;
    for (int i = t; i < CHUNK; i += 256) {
        float e = __expf(sc[i] - m);
        sc[i] = e;
        lsum += e;
    }
    for (int d = 1; d < 64; d <<= 1) lsum += __shfl_xor(lsum, d);
    if (lane == 0) wred[wave] = lsum;
    __syncthreads();  // also makes sc[] weights visible to all
    lsum = wred[0] + wred[1] + wred[2] + wred[3];

    // ---- Phase B: partial context, float4 coalesced v loads ----
    int col = t & 31;   // float4 column
    int rg = t >> 5;    // row group 0..7
    const float4* v4 = (const float4*)(v + (size_t)b * SS * DVV);
    float4 acc = make_float4(0.f, 0.f, 0.f, 0.f);
    for (int i = rg; i < CHUNK; i += 8) {
        float p = sc[i];
        float4 vv = v4[(size_t)(s0 + i) * (DVV / 4) + col];
        acc.x = fmaf(p, vv.x, acc.x);
        acc.y = fmaf(p, vv.y, acc.y);
        acc.z = fmaf(p, vv.z, acc.z);
        acc.w = fmaf(p, vv.w, acc.w);
    }
    red[t] = acc;
    __syncthreads();
    for (int off = 128; off >= 32; off >>= 1) {
        if (t < off) {
            float4 o = red[t + off];
            red[t].x += o.x; red[t].y += o.y;
            red[t].z += o.z; red[t].w += o.w;
        }
        __syncthreads();
    }
    if (t < 32)
        ((float4*)(ctx + (size_t)blk * DVV))[t] = red[t];
    if (t == 0) {
        ml[blk * 2 + 0] = m;
        ml[blk * 2 + 1] = lsum;
    }
}

// Kernel 3: merge NCHUNK chunk partials per batch with max-rescaling.
__global__ __launch_bounds__(128) void combine_kernel(
    const float* __restrict__ ml, const float* __restrict__ ctx,
    float* __restrict__ out) {
    int b = blockIdx.x;
    int t = threadIdx.x;  // 128
    __shared__ float mls[NCHUNK * 2];

    mls[t] = ml[b * NCHUNK * 2 + t];     // 128 = NCHUNK*2 exactly
    __syncthreads();

    float M = -INFINITY;
    #pragma unroll 8
    for (int c = 0; c < NCHUNK; ++c) M = fmaxf(M, mls[2 * c]);
    float L = 0.f;
    #pragma unroll 8
    for (int c = 0; c < NCHUNK; ++c) L += mls[2 * c + 1] * __expf(mls[2 * c] - M);

    float acc = 0.f;
    const float* cb = ctx + (size_t)b * NCHUNK * DVV + t;
    #pragma unroll 8
    for (int c = 0; c < NCHUNK; ++c)
        acc = fmaf(cb[(size_t)c * DVV], __expf(mls[2 * c] - M), acc);
    out[(size_t)b * DVV + t] = acc / L;
}

extern "C" void kernel_launch(void* const* d_in, const int* in_sizes, int n_in,
                              void* d_out, int out_size, void* d_ws, size_t ws_size,
                              hipStream_t stream) {
    const float* k  = (const float*)d_in[0];
    const float* q  = (const float*)d_in[1];
    const float* v  = (const float*)d_in[2];
    const float* Wk = (const float*)d_in[3];
    const float* Wq = (const float*)d_in[4];
    float* out = (float*)d_out;

    float* qt  = (float*)d_ws;                       // B*128
    float* ml  = qt + BB * OUT_DIM;                  // B*NCHUNK*2
    float* ctx = ml + (size_t)BB * NCHUNK * 2;       // B*NCHUNK*128 (2 MB)

    qt_kernel<<<BB, 512, 0, stream>>>(q, Wq, Wk, qt);
    partial_kernel<<<BB * NCHUNK, 256, 0, stream>>>(k, v, qt, ml, ctx);
    combine_kernel<<<BB, 128, 0, stream>>>(ml, ctx, out);
}

// Round 7
// 144.445 us; speedup vs baseline: 1.1818x; 1.0492x over previous
//
#include <hip/hip_runtime.h>
#include <math.h>

#define BB 64
#define SS 8192
#define IN_DIM 512
#define OUT_DIM 128
#define DVV 128
#define CHUNK 256
#define NCHUNK (SS / CHUNK)   // 32

// Kernel 1: qt[b] = (Wk @ (q[b] @ Wq)) / sqrt(OUT_DIM)   (512 threads, 4-way split-K)
__global__ __launch_bounds__(512) void qt_kernel(const float* __restrict__ q,
                          const float* __restrict__ Wq,
                          const float* __restrict__ Wk,
                          float* __restrict__ qt) {
    int b = blockIdx.x;
    int t = threadIdx.x;
    int e = t & 127;          // output index
    int h = t >> 7;           // split 0..3
    __shared__ float part[4][OUT_DIM];
    __shared__ float qs[OUT_DIM];

    const float* qb = q + (size_t)b * IN_DIM;
    float acc = 0.f;
    for (int i = h * (IN_DIM / 4); i < (h + 1) * (IN_DIM / 4); ++i)
        acc = fmaf(qb[i], Wq[(size_t)i * OUT_DIM + e], acc);
    part[h][e] = acc;
    __syncthreads();
    if (h == 0) qs[e] = part[0][e] + part[1][e] + part[2][e] + part[3][e];
    __syncthreads();

    float a2 = 0.f;
    const float* wkrow = Wk + (size_t)e * OUT_DIM;
    for (int i = h * (OUT_DIM / 4); i < (h + 1) * (OUT_DIM / 4); ++i)
        a2 = fmaf(wkrow[i], qs[i], a2);
    part[h][e] = a2;
    __syncthreads();
    if (h == 0)
        qt[(size_t)b * OUT_DIM + e] =
            (part[0][e] + part[1][e] + part[2][e] + part[3][e]) * 0.08838834764831845f;
}

// Kernel 2: EXACT R0 partial kernel (CHUNK=256, 2048 blocks) — the measured
// best streaming configuration (~5.0 TB/s logical). Do not perturb.
__global__ __launch_bounds__(256) void partial_kernel(
    const float* __restrict__ k, const float* __restrict__ v,
    const float* __restrict__ qt, float* __restrict__ ml,
    float* __restrict__ ctx) {
    int blk = blockIdx.x;
    int b = blk / NCHUNK;
    int c = blk % NCHUNK;
    int s0 = c * CHUNK;
    int t = threadIdx.x;
    int wave = t >> 6, lane = t & 63, half = lane >> 5, l32 = lane & 31;

    __shared__ float4 qts4[OUT_DIM / 4];
    __shared__ float sc[CHUNK];
    __shared__ float4 red[256];
    __shared__ float wred[4];

    if (t < OUT_DIM / 4)
        qts4[t] = ((const float4*)(qt + (size_t)b * OUT_DIM))[t];
    __syncthreads();

    // ---- Phase A: scores for CHUNK rows, float4 coalesced k loads ----
    const float4* k4 = (const float4*)(k + (size_t)b * SS * OUT_DIM);
    float4 qv = qts4[l32];
    for (int i = wave * 2 + half; i < CHUNK; i += 8) {
        float4 kv = k4[(size_t)(s0 + i) * (OUT_DIM / 4) + l32];
        float p = kv.x * qv.x + kv.y * qv.y + kv.z * qv.z + kv.w * qv.w;
        p += __shfl_xor(p, 1);
        p += __shfl_xor(p, 2);
        p += __shfl_xor(p, 4);
        p += __shfl_xor(p, 8);
        p += __shfl_xor(p, 16);
        if (l32 == 0) sc[i] = p;
    }
    __syncthreads();

    // ---- chunk max ----
    float m = -INFINITY;
    for (int i = t; i < CHUNK; i += 256) m = fmaxf(m, sc[i]);
    for (int d = 1; d < 64; d <<= 1) m = fmaxf(m, __shfl_xor(m, d));
    if (lane == 0) wred[wave] = m;
    __syncthreads();
    m = fmaxf(fmaxf(wred[0], wred[1]), fmaxf(wred[2], wred[3]));
    __syncthreads();  // protect wred reuse

    // ---- exp + chunk sum ----
    float lsum = 0.f;
    for (int i = t; i < CHUNK; i += 256) {
        float e = __expf(sc[i] - m);
        sc[i] = e;
        lsum += e;
    }
    for (int d = 1; d < 64; d <<= 1) lsum += __shfl_xor(lsum, d);
    if (lane == 0) wred[wave] = lsum;
    __syncthreads();  // also makes sc[] weights visible to all
    lsum = wred[0] + wred[1] + wred[2] + wred[3];

    // ---- Phase B: partial context, float4 coalesced v loads ----
    int col = t & 31;   // float4 column
    int rg = t >> 5;    // row group 0..7
    const float4* v4 = (const float4*)(v + (size_t)b * SS * DVV);
    float4 acc = make_float4(0.f, 0.f, 0.f, 0.f);
    for (int i = rg; i < CHUNK; i += 8) {
        float p = sc[i];
        float4 vv = v4[(size_t)(s0 + i) * (DVV / 4) + col];
        acc.x = fmaf(p, vv.x, acc.x);
        acc.y = fmaf(p, vv.y, acc.y);
        acc.z = fmaf(p, vv.z, acc.z);
        acc.w = fmaf(p, vv.w, acc.w);
    }
    red[t] = acc;
    __syncthreads();
    for (int off = 128; off >= 32; off >>= 1) {
        if (t < off) {
            float4 o = red[t + off];
            red[t].x += o.x; red[t].y += o.y;
            red[t].z += o.z; red[t].w += o.w;
        }
        __syncthreads();
    }
    if (t < 32)
        ((float4*)(ctx + ((size_t)(b * NCHUNK + c)) * DVV))[t] = red[t];
    if (t == 0) {
        ml[(b * NCHUNK + c) * 2 + 0] = m;
        ml[(b * NCHUNK + c) * 2 + 1] = lsum;
    }
}

// Kernel 3: EXACT R0 combine kernel.
__global__ void combine_kernel(const float* __restrict__ ml,
                               const float* __restrict__ ctx,
                               float* __restrict__ out) {
    int b = blockIdx.x;
    int t = threadIdx.x;  // 128
    __shared__ float ms, ls;
    float m = -INFINITY;
    if (t < NCHUNK) m = ml[(b * NCHUNK + t) * 2];
    for (int d = 1; d < 32; d <<= 1) m = fmaxf(m, __shfl_xor(m, d));
    if (t == 0) ms = m;
    __syncthreads();
    m = ms;
    float l = 0.f;
    if (t < NCHUNK)
        l = ml[(b * NCHUNK + t) * 2 + 1] * __expf(ml[(b * NCHUNK + t) * 2] - m);
    for (int d = 1; d < 32; d <<= 1) l += __shfl_xor(l, d);
    if (t == 0) ls = l;
    __syncthreads();
    l = ls;
    float acc = 0.f;
    for (int c2 = 0; c2 < NCHUNK; ++c2) {
        float w = __expf(ml[(b * NCHUNK + c2) * 2] - m);
        acc = fmaf(ctx[((size_t)(b * NCHUNK + c2)) * DVV + t], w, acc);
    }
    out[(size_t)b * DVV + t] = acc / l;
}

extern "C" void kernel_launch(void* const* d_in, const int* in_sizes, int n_in,
                              void* d_out, int out_size, void* d_ws, size_t ws_size,
                              hipStream_t stream) {
    const float* k  = (const float*)d_in[0];
    const float* q  = (const float*)d_in[1];
    const float* v  = (const float*)d_in[2];
    const float* Wk = (const float*)d_in[3];
    const float* Wq = (const float*)d_in[4];
    float* out = (float*)d_out;

    float* qt  = (float*)d_ws;                 // B*128 floats
    float* ml  = qt + BB * OUT_DIM;            // B*NCHUNK*2 floats
    float* ctx = ml + BB * NCHUNK * 2;         // B*NCHUNK*128 floats (~1 MB total)

    qt_kernel<<<BB, 512, 0, stream>>>(q, Wq, Wk, qt);
    partial_kernel<<<BB * NCHUNK, 256, 0, stream>>>(k, v, qt, ml, ctx);
    combine_kernel<<<BB, DVV, 0, stream>>>(ml, ctx, out);
}